// Round 16
// baseline (568.740 us; speedup 1.0000x reference)
//
#include <hip/hip_runtime.h>
#include <hip/hip_cooperative_groups.h>
#include <math.h>

namespace cg = cooperative_groups;

#define Bb 16
#define Nn 2048
#define Dd 512
#define Kk 8

constexpr float TAU = 0.07f;
constexpr float EPSc = 1e-6f;
constexpr float LN_EPS = 1e-5f;
constexpr float NORM_EPS = 1e-12f;
constexpr float SCALE = 0.04419417382415922f; // 1/sqrt(512)

// output layout (floats)
constexpr size_t OUT_FFG  = 0;
constexpr size_t OUT_FBG  = (size_t)Bb*Nn*Dd;
constexpr size_t OUT_PBG  = OUT_FBG + (size_t)Bb*Nn*Dd;
constexpr size_t OUT_SSEM = OUT_PBG + (size_t)Bb*Kk*Dd;
constexpr size_t OUT_LOSS = OUT_SSEM + (size_t)Bb*Nn;

// ws layout (floats)
constexpr int    NCH = 64;                                      // chunks of 32 tokens
constexpr size_t WS_PBPART = 0;                                 // B*NCH*K*D = 4M
constexpr size_t WS_SUMW   = WS_PBPART + (size_t)Bb*NCH*Kk*Dd;  // B*NCH*8
constexpr size_t WS_M      = WS_SUMW + (size_t)Bb*NCH*Kk;       // B*64
constexpr size_t WS_IDEN   = WS_M + Bb*64;                      // B*K
constexpr size_t WS_INP    = WS_IDEN + Bb*Kk;                   // B*K
constexpr size_t WS_P1     = WS_INP + Bb*Kk;                    // B*K
constexpr size_t WS_FQN    = WS_P1 + Bb*Kk;                     // B*D
constexpr size_t WS_SP     = WS_FQN + (size_t)Bb*Dd;            // 1024*64
constexpr size_t WS_P5A    = WS_SP + (size_t)Bb*NCH*64;         // 1024*2
constexpr size_t WS_P5B    = WS_P5A + 2048;                     // 1024*2

__device__ __forceinline__ float dot4(float4 a, float4 b) {
    return a.x*b.x + a.y*b.y + a.z*b.z + a.w*b.w;
}

using f32x4 = __attribute__((ext_vector_type(4))) float;
__device__ __forceinline__ void nt_store4(float* p, float4 v) {
    f32x4 t; t.x = v.x; t.y = v.y; t.z = v.z; t.w = v.w;
    __builtin_nontemporal_store(t, (f32x4*)p);
}

struct SK1 { float qls[Kk*Dd]; float wlds[32][8]; float swsum[8][8]; };
struct SK3 { float pb[Kk*Dd]; float sumwseg[8][8]; float swt[8]; float redq[8];
             float mseg[64][8]; float p1seg[8][8]; };
struct SK5 { float pls[Kk*Dd]; float scl[32][12]; float Ml[64];
             float idenl[8]; float inpl[8]; float p1l[8]; float al[8][4]; float swp[8][64]; };
struct SK8 { float Sf[Bb][64]; float Mf[Bb][64]; float Af[Bb][64]; float trb[Bb]; double redd[8][4]; };
union SMem { SK1 k1; SK3 k3; SK5 k5; SK8 k8; };

// ================= cooperative mega kernel (512 blocks x 512 thr) =================
__global__ __launch_bounds__(512, 4) void mega_kernel(
    const float* __restrict__ f_raw, const float* __restrict__ f_q,
    const int* __restrict__ gt_mask, const float* __restrict__ q_bg,
    const float* __restrict__ alpha_p, const float* __restrict__ ln_w,
    const float* __restrict__ ln_b, float* __restrict__ out,
    float* __restrict__ ws)
{
    cg::grid_group grid = cg::this_grid();
    __shared__ SMem sm;
    int tid = threadIdx.x, lane = tid & 63, wave = tid >> 6;   // 8 waves
    int blk = blockIdx.x;
    int b = blk >> 5;
    int cbase = (blk & 31) * 2;
    float* out_pbg  = out + OUT_PBG;
    float* out_ffg  = out + OUT_FFG;
    float* out_fbg  = out + OUT_FBG;
    float* out_ssem = out + OUT_SSEM;

    // ---------------- Phase 1: k1 (2 chunks) ----------------
    {
        SK1& s = sm.k1;
        for (int e = tid; e < Kk*Dd; e += 512) s.qls[e] = q_bg[e];
        __syncthreads();
        int sub = lane >> 4, idx = lane & 15;
        for (int qc = 0; qc < 2; ++qc) {
            int chunk = cbase + qc;
            int tok0 = chunk * 32;
            int tokl = wave*4 + sub;
            const float* ftok = f_raw + ((size_t)b*Nn + tok0 + tokl)*Dd;
            float a[8] = {0,0,0,0,0,0,0,0};
            #pragma unroll
            for (int cc = 0; cc < 8; ++cc) {
                int o = cc*64 + idx*4;
                float4 f4 = *(const float4*)(ftok + o);
                #pragma unroll
                for (int k = 0; k < 8; ++k) {
                    float4 q4 = *(const float4*)&s.qls[k*Dd + o];
                    a[k] += dot4(f4, q4);
                }
            }
            #pragma unroll
            for (int m = 1; m <= 8; m <<= 1) {
                #pragma unroll
                for (int k = 0; k < 8; ++k) a[k] += __shfl_xor(a[k], m, 64);
            }
            float w8[8];
            #pragma unroll
            for (int k = 0; k < 8; ++k) w8[k] = expf(a[k]*SCALE);
            if (idx == 0) {
                *(float4*)&s.wlds[tokl][0] = make_float4(w8[0],w8[1],w8[2],w8[3]);
                *(float4*)&s.wlds[tokl][4] = make_float4(w8[4],w8[5],w8[6],w8[7]);
            }
            float sw[8];
            #pragma unroll
            for (int k = 0; k < 8; ++k) sw[k] = (idx == 0) ? w8[k] : 0.f;
            #pragma unroll
            for (int k = 0; k < 8; ++k) {
                sw[k] += __shfl_xor(sw[k], 16, 64);
                sw[k] += __shfl_xor(sw[k], 32, 64);
            }
            if (lane == 0) {
                *(float4*)&s.swsum[wave][0] = make_float4(sw[0],sw[1],sw[2],sw[3]);
                *(float4*)&s.swsum[wave][4] = make_float4(sw[4],sw[5],sw[6],sw[7]);
            }
            __syncthreads();
            if (tid < 8) {
                float ssum = 0.f;
                #pragma unroll
                for (int w = 0; w < 8; ++w) ssum += s.swsum[w][tid];
                ws[WS_SUMW + (size_t)(b*NCH + chunk)*8 + tid] = ssum;
            }
            int d = tid;
            const float* fcol = f_raw + ((size_t)b*Nn + tok0)*Dd + d;
            float acc[8] = {0,0,0,0,0,0,0,0};
            #pragma unroll 4
            for (int nn = 0; nn < 32; ++nn) {
                float f = fcol[(size_t)nn*Dd];
                float4 wa = *(const float4*)&s.wlds[nn][0];
                float4 wb = *(const float4*)&s.wlds[nn][4];
                acc[0]+=wa.x*f; acc[1]+=wa.y*f; acc[2]+=wa.z*f; acc[3]+=wa.w*f;
                acc[4]+=wb.x*f; acc[5]+=wb.y*f; acc[6]+=wb.z*f; acc[7]+=wb.w*f;
            }
            #pragma unroll
            for (int k = 0; k < 8; ++k)
                ws[WS_PBPART + ((size_t)(b*NCH + chunk)*8 + k)*Dd + d] = acc[k];
            __syncthreads();   // protect wlds/swsum for next chunk
        }
    }
    __threadfence();
    grid.sync();

    // ---------------- Phase 2: k3b (blocks < 16) ----------------
    if (blk < Bb) {
        SK3& s = sm.k3;
        int bb = blk;
        if (tid < 64) {
            int k = tid & 7, sg = tid >> 3;
            float ssum = 0.f;
            #pragma unroll
            for (int i = 0; i < 8; ++i)
                ssum += ws[WS_SUMW + (size_t)(bb*NCH + sg*8 + i)*8 + k];
            s.sumwseg[sg][k] = ssum;
        }
        __syncthreads();
        if (tid < 8) {
            float ssum = 0.f;
            #pragma unroll
            for (int sg = 0; sg < 8; ++sg) ssum += s.sumwseg[sg][tid];
            s.swt[tid] = 1.f/ssum;
        }
        float qv = f_q[bb*Dd + tid];
        float p2 = qv*qv;
        #pragma unroll
        for (int off = 32; off >= 1; off >>= 1) p2 += __shfl_xor(p2, off, 64);
        if (lane == 0) s.redq[wave] = p2;
        __syncthreads();   // swt + redq ready
        #pragma unroll
        for (int rep = 0; rep < 2; ++rep) {
            int e4 = (tid + rep*512)*4;
            float4 s4 = make_float4(0.f,0.f,0.f,0.f);
            #pragma unroll 4
            for (int ns = 0; ns < NCH; ++ns) {
                float4 p = *(const float4*)(ws + WS_PBPART + (size_t)(bb*NCH + ns)*(Kk*Dd) + e4);
                s4.x += p.x; s4.y += p.y; s4.z += p.z; s4.w += p.w;
            }
            float swv = s.swt[e4 >> 9];
            s4.x *= swv; s4.y *= swv; s4.z *= swv; s4.w *= swv;
            *(float4*)&s.pb[e4] = s4;
            *(float4*)(out_pbg + (size_t)bb*Kk*Dd + e4) = s4;
        }
        {
            float ssum = 0.f;
            #pragma unroll
            for (int w = 0; w < 8; ++w) ssum += s.redq[w];
            float invq = 1.f/fmaxf(sqrtf(ssum), NORM_EPS);
            ws[WS_FQN + (size_t)bb*Dd + tid] = qv*invq;
        }
        __syncthreads();   // pb ready
        {
            int pair = tid >> 3, seg = tid & 7;
            int i = pair >> 3, j = pair & 7;
            float ssum = 0.f;
            for (int d = seg*64; d < seg*64 + 64; ++d) ssum += s.pb[i*Dd + d]*s.pb[j*Dd + d];
            s.mseg[pair][seg] = ssum;
        }
        if (tid < 64) {
            int k = tid >> 3, sg = tid & 7;
            float s1 = 0.f;
            for (int d = sg*64; d < sg*64 + 64; ++d) s1 += s.pb[k*Dd + d];
            s.p1seg[k][sg] = s1;
        }
        __syncthreads();
        if (tid < 64) {
            float m = 0.f;
            #pragma unroll
            for (int sg = 0; sg < 8; ++sg) m += s.mseg[tid][sg];
            ws[WS_M + bb*64 + tid] = m;
            if ((tid >> 3) == (tid & 7)) {
                int k = tid & 7;
                ws[WS_IDEN + bb*Kk + k] = 1.f/(m + EPSc);
                ws[WS_INP + bb*Kk + k] = 1.f/fmaxf(sqrtf(m), NORM_EPS);
            }
        }
        if (tid < 8) {
            float s1 = 0.f;
            #pragma unroll
            for (int sg = 0; sg < 8; ++sg) s1 += s.p1seg[tid][sg];
            ws[WS_P1 + bb*Kk + tid] = s1;
        }
    }
    __threadfence();
    grid.sync();

    // ---------------- Phase 3: k5 (2 chunks) ----------------
    {
        SK5& s = sm.k5;
        for (int e = tid; e < Kk*Dd; e += 512) s.pls[e] = out_pbg[(size_t)b*Kk*Dd + e];
        if (tid >= 416 && tid < 480) s.Ml[tid-416] = ws[WS_M + b*64 + (tid-416)];
        else if (tid >= 480 && tid < 504) {
            int g = (tid-480) >> 3, k = (tid-480) & 7;
            if      (g == 0) s.idenl[k] = ws[WS_IDEN + b*8 + k];
            else if (g == 1) s.inpl[k]  = ws[WS_INP  + b*8 + k];
            else             s.p1l[k]   = ws[WS_P1   + b*8 + k];
        }
        __syncthreads();
        int sub = lane >> 4, idx = lane & 15;
        for (int qc = 0; qc < 2; ++qc) {
            int chunk = cbase + qc;
            int tok0 = chunk * 32;
            int gi = blk*2 + qc;
            int tokl = wave*4 + sub;
            const float* ftok = f_raw + ((size_t)b*Nn + tok0 + tokl)*Dd;
            float A[8] = {0,0,0,0,0,0,0,0};
            float nf2 = 0.f, sf = 0.f;
            #pragma unroll
            for (int cc = 0; cc < 8; ++cc) {
                int o = cc*64 + idx*4;
                float4 f4 = *(const float4*)(ftok + o);
                #pragma unroll
                for (int k = 0; k < 8; ++k) {
                    float4 p4 = *(const float4*)&s.pls[k*Dd + o];
                    A[k] += dot4(f4, p4);
                }
                nf2 += dot4(f4, f4);
                sf  += f4.x + f4.y + f4.z + f4.w;
            }
            #pragma unroll
            for (int m = 1; m <= 8; m <<= 1) {
                #pragma unroll
                for (int k = 0; k < 8; ++k) A[k] += __shfl_xor(A[k], m, 64);
                nf2 += __shfl_xor(nf2, m, 64);
                sf  += __shfl_xor(sf, m, 64);
            }
            float wcsum, wdsum;
            {
                float alpha = alpha_p[0];
                float coef[8], sca = 0.f, sp1 = 0.f;
                #pragma unroll
                for (int k = 0; k < 8; ++k) {
                    coef[k] = A[k]*s.idenl[k];
                    sca += coef[k]*A[k];
                    sp1 += coef[k]*s.p1l[k];
                }
                float quad = 0.f;
                #pragma unroll
                for (int i = 0; i < 8; ++i) {
                    float ti = 0.f;
                    #pragma unroll
                    for (int j = 0; j < 8; ++j) ti += s.Ml[i*8+j]*coef[j];
                    quad += coef[i]*ti;
                }
                float sx  = sf - alpha*sp1;
                float sxx = nf2 - 2.f*alpha*sca + alpha*alpha*quad;
                float mu  = sx*(1.f/Dd);
                float var = sxx*(1.f/Dd) - mu*mu;
                float rstd = 1.f/sqrtf(fmaxf(var, 0.f) + LN_EPS);
                float invnf = 1.f/fmaxf(sqrtf(nf2), NORM_EPS);
                float cmin = 1e30f;
                #pragma unroll
                for (int k = 0; k < 8; ++k) cmin = fminf(cmin, 1.f - A[k]*invnf*s.inpl[k]);
                float invnb = 1.f/fmaxf(sqrtf(quad), NORM_EPS);
                float inb2 = invnb*invnb;
                float gnn = quad*inb2;
                float dloc = gnn*gnn;
                float cp[8];
                #pragma unroll
                for (int k = 0; k < 8; ++k) cp[k] = coef[k]*invnb;
                if (idx == 0) {
                    *(float4*)&s.scl[tokl][0] = make_float4(coef[0],coef[1],coef[2],coef[3]);
                    *(float4*)&s.scl[tokl][4] = make_float4(coef[4],coef[5],coef[6],coef[7]);
                    *(float2*)&s.scl[tokl][8] = make_float2(mu, rstd);
                }
                float spv[4];
                #pragma unroll
                for (int q = 0; q < 4; ++q) {
                    int e = idx*4 + q;
                    spv[q] = cp[e >> 3]*cp[e & 7];
                }
                #pragma unroll
                for (int q = 0; q < 4; ++q) {
                    spv[q] += __shfl_xor(spv[q], 16, 64);
                    spv[q] += __shfl_xor(spv[q], 32, 64);
                }
                if (lane < 16)
                    *(float4*)&s.swp[wave][idx*4] = make_float4(spv[0],spv[1],spv[2],spv[3]);
                float cv = (idx == 0) ? cmin : 0.f;
                float dv = (idx == 0) ? dloc : 0.f;
                cv += __shfl_xor(cv, 16, 64); cv += __shfl_xor(cv, 32, 64);
                dv += __shfl_xor(dv, 16, 64); dv += __shfl_xor(dv, 32, 64);
                wcsum = cv; wdsum = dv;
            }
            // phase B: stream (no barrier, scl same-wave)
            float alpha = alpha_p[0];
            float ng2h[4], dqh[4];
            {
                int d0 = lane*4;
                float4 pbr[8];
                #pragma unroll
                for (int k = 0; k < 8; ++k) pbr[k] = *(const float4*)&s.pls[k*Dd + d0];
                float4 w4 = *(const float4*)(ln_w + d0);
                float4 b4 = *(const float4*)(ln_b + d0);
                float4 q4 = *(const float4*)(ws + WS_FQN + b*Dd + d0);
                #pragma unroll
                for (int t = 0; t < 4; ++t) {
                    int lt = wave*4 + t;
                    float4 cA = *(const float4*)&s.scl[lt][0];
                    float4 cB = *(const float4*)&s.scl[lt][4];
                    float2 mr = *(const float2*)&s.scl[lt][8];
                    size_t rowoff = ((size_t)b*Nn + tok0 + lt)*Dd;
                    float4 fv = *(const float4*)(f_raw + rowoff + d0);
                    float4 fb;
                    fb.x = cA.x*pbr[0].x + cA.y*pbr[1].x + cA.z*pbr[2].x + cA.w*pbr[3].x
                         + cB.x*pbr[4].x + cB.y*pbr[5].x + cB.z*pbr[6].x + cB.w*pbr[7].x;
                    fb.y = cA.x*pbr[0].y + cA.y*pbr[1].y + cA.z*pbr[2].y + cA.w*pbr[3].y
                         + cB.x*pbr[4].y + cB.y*pbr[5].y + cB.z*pbr[6].y + cB.w*pbr[7].y;
                    fb.z = cA.x*pbr[0].z + cA.y*pbr[1].z + cA.z*pbr[2].z + cA.w*pbr[3].z
                         + cB.x*pbr[4].z + cB.y*pbr[5].z + cB.z*pbr[6].z + cB.w*pbr[7].z;
                    fb.w = cA.x*pbr[0].w + cA.y*pbr[1].w + cA.z*pbr[2].w + cA.w*pbr[3].w
                         + cB.x*pbr[4].w + cB.y*pbr[5].w + cB.z*pbr[6].w + cB.w*pbr[7].w;
                    nt_store4(out_fbg + rowoff + d0, fb);
                    float4 g;
                    g.x = (fv.x - alpha*fb.x - mr.x)*mr.y*w4.x + b4.x;
                    g.y = (fv.y - alpha*fb.y - mr.x)*mr.y*w4.y + b4.y;
                    g.z = (fv.z - alpha*fb.z - mr.x)*mr.y*w4.z + b4.z;
                    g.w = (fv.w - alpha*fb.w - mr.x)*mr.y*w4.w + b4.w;
                    nt_store4(out_ffg + rowoff + d0, g);
                    ng2h[t] = dot4(g, g);
                    dqh[t]  = dot4(g, q4);
                }
            }
            float align_s = 0.f, align_c = 0.f;
            {
                int d0 = 256 + lane*4;
                float4 pbr[8];
                #pragma unroll
                for (int k = 0; k < 8; ++k) pbr[k] = *(const float4*)&s.pls[k*Dd + d0];
                float4 w4 = *(const float4*)(ln_w + d0);
                float4 b4 = *(const float4*)(ln_b + d0);
                float4 q4 = *(const float4*)(ws + WS_FQN + b*Dd + d0);
                #pragma unroll
                for (int t = 0; t < 4; ++t) {
                    int lt = wave*4 + t;
                    size_t n = (size_t)b*Nn + tok0 + lt;
                    float4 cA = *(const float4*)&s.scl[lt][0];
                    float4 cB = *(const float4*)&s.scl[lt][4];
                    float2 mr = *(const float2*)&s.scl[lt][8];
                    size_t rowoff = n*(size_t)Dd;
                    float4 fv = *(const float4*)(f_raw + rowoff + d0);
                    float4 fb;
                    fb.x = cA.x*pbr[0].x + cA.y*pbr[1].x + cA.z*pbr[2].x + cA.w*pbr[3].x
                         + cB.x*pbr[4].x + cB.y*pbr[5].x + cB.z*pbr[6].x + cB.w*pbr[7].x;
                    fb.y = cA.x*pbr[0].y + cA.y*pbr[1].y + cA.z*pbr[2].y + cA.w*pbr[3].y
                         + cB.x*pbr[4].y + cB.y*pbr[5].y + cB.z*pbr[6].y + cB.w*pbr[7].y;
                    fb.z = cA.x*pbr[0].z + cA.y*pbr[1].z + cA.z*pbr[2].z + cA.w*pbr[3].z
                         + cB.x*pbr[4].z + cB.y*pbr[5].z + cB.z*pbr[6].z + cB.w*pbr[7].z;
                    fb.w = cA.x*pbr[0].w + cA.y*pbr[1].w + cA.z*pbr[2].w + cA.w*pbr[3].w
                         + cB.x*pbr[4].w + cB.y*pbr[5].w + cB.z*pbr[6].w + cB.w*pbr[7].w;
                    nt_store4(out_fbg + rowoff + d0, fb);
                    float4 g;
                    g.x = (fv.x - alpha*fb.x - mr.x)*mr.y*w4.x + b4.x;
                    g.y = (fv.y - alpha*fb.y - mr.x)*mr.y*w4.y + b4.y;
                    g.z = (fv.z - alpha*fb.z - mr.x)*mr.y*w4.z + b4.z;
                    g.w = (fv.w - alpha*fb.w - mr.x)*mr.y*w4.w + b4.w;
                    nt_store4(out_ffg + rowoff + d0, g);
                    float ng2 = ng2h[t] + dot4(g, g);
                    float dq  = dqh[t]  + dot4(g, q4);
                    #pragma unroll
                    for (int off = 32; off >= 1; off >>= 1) {
                        ng2 += __shfl_xor(ng2, off, 64);
                        dq  += __shfl_xor(dq,  off, 64);
                    }
                    float sim = dq * (1.f/fmaxf(sqrtf(ng2), NORM_EPS));
                    float ssem = 1.f/(1.f + expf(-sim*(1.f/TAU)));
                    if (lane == 0) {
                        out_ssem[n] = ssem;
                        if (gt_mask[n] != 0) { align_s += -logf(fmaxf(ssem, EPSc)); align_c += 1.f; }
                    }
                }
            }
            if (lane == 0) {
                s.al[wave][0] = align_s; s.al[wave][1] = align_c;
                s.al[wave][2] = wcsum;   s.al[wave][3] = wdsum;
            }
            __syncthreads();
            if (tid < 64) {
                float ssum = 0.f;
                #pragma unroll
                for (int w = 0; w < 8; ++w) ssum += s.swp[w][tid];
                ws[WS_SP + (size_t)gi*64 + tid] = ssum;
            }
            if (tid == 0) {
                float as = 0.f, ac = 0.f, cs = 0.f, ds = 0.f;
                #pragma unroll
                for (int w = 0; w < 8; ++w) {
                    as += s.al[w][0]; ac += s.al[w][1]; cs += s.al[w][2]; ds += s.al[w][3];
                }
                ws[WS_P5B + (size_t)gi*2 + 0] = as;
                ws[WS_P5B + (size_t)gi*2 + 1] = ac;
                ws[WS_P5A + (size_t)gi*2 + 0] = cs;
                ws[WS_P5A + (size_t)gi*2 + 1] = ds;
            }
            __syncthreads();   // protect scl/al/swp for next chunk
        }
    }
    __threadfence();
    grid.sync();

    // ---------------- Phase 4: k8 (block 0) ----------------
    if (blk == 0) {
        SK8& s = sm.k8;
        #pragma unroll
        for (int r = 0; r < 2; ++r) {
            int bb = wave + r*8, e = lane;
            float ssum = 0.f;
            #pragma unroll 8
            for (int c = 0; c < NCH; ++c)
                ssum += ws[WS_SP + (size_t)(bb*64 + c)*64 + e];
            s.Sf[bb][e] = ssum;
            s.Mf[bb][e] = ws[WS_M + bb*64 + e];
        }
        __syncthreads();
        #pragma unroll
        for (int r = 0; r < 2; ++r) {
            int bb = wave + r*8, e = lane;
            int ii = e >> 3, jj = e & 7;
            float a = 0.f;
            #pragma unroll
            for (int k = 0; k < 8; ++k) a += s.Mf[bb][ii*8+k]*s.Sf[bb][k*8+jj];
            s.Af[bb][e] = a;
        }
        __syncthreads();
        #pragma unroll
        for (int r = 0; r < 2; ++r) {
            int bb = wave + r*8, e = lane;
            float p = s.Af[bb][e]*s.Af[bb][(e & 7)*8 + (e >> 3)];
            #pragma unroll
            for (int off = 32; off >= 1; off >>= 1) p += __shfl_xor(p, off, 64);
            if (lane == 0) s.trb[bb] = p;
        }
        double c = 0.0, dg = 0.0, as = 0.0, ac = 0.0;
        #pragma unroll
        for (int r = 0; r < 2; ++r) {
            int idx2 = tid + r*512;
            c  += (double)ws[WS_P5A + (size_t)idx2*2 + 0];
            dg += (double)ws[WS_P5A + (size_t)idx2*2 + 1];
            as += (double)ws[WS_P5B + (size_t)idx2*2 + 0];
            ac += (double)ws[WS_P5B + (size_t)idx2*2 + 1];
        }
        #pragma unroll
        for (int off = 32; off >= 1; off >>= 1) {
            c  += __shfl_xor(c,  off, 64);
            dg += __shfl_xor(dg, off, 64);
            as += __shfl_xor(as, off, 64);
            ac += __shfl_xor(ac, off, 64);
        }
        if (lane == 0) { s.redd[wave][0]=c; s.redd[wave][1]=dg; s.redd[wave][2]=as; s.redd[wave][3]=ac; }
        __syncthreads();
        if (tid == 0) {
            double ct=0, dgt=0, ast=0, act=0, trt=0;
            for (int w = 0; w < 8; ++w) {
                ct += s.redd[w][0]; dgt += s.redd[w][1]; ast += s.redd[w][2]; act += s.redd[w][3];
            }
            for (int bb = 0; bb < Bb; ++bb) trt += (double)s.trb[bb];
            float* out_loss = out + OUT_LOSS;
            out_loss[0] = (float)(ct / (double)((size_t)Bb*Nn));
            out_loss[1] = (float)((trt - dgt) / ((double)Bb*(double)Nn*(double)Nn));
            out_loss[2] = (float)(act > 0.0 ? ast / (act > 1.0 ? act : 1.0) : 0.0);
        }
    }
}

// ================= fallback 4-kernel path (round-15 proven) =================
__global__ __launch_bounds__(512, 4) void k1_scores(const float* __restrict__ f_raw,
                                                    const float* __restrict__ q_bg,
                                                    float* __restrict__ ws) {
    int b = blockIdx.x >> 6;
    int chunk = blockIdx.x & 63;
    int tok0 = chunk * 32;
    int tid = threadIdx.x, lane = tid & 63, wave = tid >> 6;
    __shared__ float qls[Kk*Dd];
    __shared__ float wlds[32][8];
    __shared__ float swsum[8][8];
    for (int e = tid; e < Kk*Dd; e += 512) qls[e] = q_bg[e];
    __syncthreads();
    int sub = lane >> 4, idx = lane & 15;
    int tokl = wave*4 + sub;
    const float* ftok = f_raw + ((size_t)b*Nn + tok0 + tokl)*Dd;
    float a[8] = {0,0,0,0,0,0,0,0};
    #pragma unroll
    for (int cc = 0; cc < 8; ++cc) {
        int o = cc*64 + idx*4;
        float4 f4 = *(const float4*)(ftok + o);
        #pragma unroll
        for (int k = 0; k < 8; ++k) {
            float4 q4 = *(const float4*)&qls[k*Dd + o];
            a[k] += dot4(f4, q4);
        }
    }
    #pragma unroll
    for (int m = 1; m <= 8; m <<= 1) {
        #pragma unroll
        for (int k = 0; k < 8; ++k) a[k] += __shfl_xor(a[k], m, 64);
    }
    float w8[8];
    #pragma unroll
    for (int k = 0; k < 8; ++k) w8[k] = expf(a[k]*SCALE);
    if (idx == 0) {
        *(float4*)&wlds[tokl][0] = make_float4(w8[0],w8[1],w8[2],w8[3]);
        *(float4*)&wlds[tokl][4] = make_float4(w8[4],w8[5],w8[6],w8[7]);
    }
    float sw[8];
    #pragma unroll
    for (int k = 0; k < 8; ++k) sw[k] = (idx == 0) ? w8[k] : 0.f;
    #pragma unroll
    for (int k = 0; k < 8; ++k) {
        sw[k] += __shfl_xor(sw[k], 16, 64);
        sw[k] += __shfl_xor(sw[k], 32, 64);
    }
    if (lane == 0) {
        *(float4*)&swsum[wave][0] = make_float4(sw[0],sw[1],sw[2],sw[3]);
        *(float4*)&swsum[wave][4] = make_float4(sw[4],sw[5],sw[6],sw[7]);
    }
    __syncthreads();
    if (tid < 8) {
        float s = 0.f;
        #pragma unroll
        for (int w = 0; w < 8; ++w) s += swsum[w][tid];
        ws[WS_SUMW + (size_t)(b*NCH + chunk)*8 + tid] = s;
    }
    int d = tid;
    const float* fcol = f_raw + ((size_t)b*Nn + tok0)*Dd + d;
    float acc[8] = {0,0,0,0,0,0,0,0};
    #pragma unroll 4
    for (int nn = 0; nn < 32; ++nn) {
        float f = fcol[(size_t)nn*Dd];
        float4 wa = *(const float4*)&wlds[nn][0];
        float4 wb = *(const float4*)&wlds[nn][4];
        acc[0]+=wa.x*f; acc[1]+=wa.y*f; acc[2]+=wa.z*f; acc[3]+=wa.w*f;
        acc[4]+=wb.x*f; acc[5]+=wb.y*f; acc[6]+=wb.z*f; acc[7]+=wb.w*f;
    }
    #pragma unroll
    for (int k = 0; k < 8; ++k)
        ws[WS_PBPART + ((size_t)(b*NCH + chunk)*8 + k)*Dd + d] = acc[k];
}

__global__ __launch_bounds__(1024) void k3b_all(float* __restrict__ ws,
                                                float* __restrict__ out_pbg,
                                                const float* __restrict__ f_q) {
    int b = blockIdx.x, tid = threadIdx.x;
    int lane = tid & 63, wave = tid >> 6;
    __shared__ float pb[Kk*Dd];
    __shared__ float swt[8];
    __shared__ float sumwseg[8][8];
    __shared__ float redq[16];
    __shared__ float mseg[64][8];
    __shared__ float p1seg[8][8];
    if (tid < 64) {
        int k = tid & 7, sg = tid >> 3;
        float s = 0.f;
        #pragma unroll
        for (int i = 0; i < 8; ++i)
            s += ws[WS_SUMW + (size_t)(b*NCH + sg*8 + i)*8 + k];
        sumwseg[sg][k] = s;
    }
    __syncthreads();
    if (tid < 8) {
        float s = 0.f;
        #pragma unroll
        for (int sg = 0; sg < 8; ++sg) s += sumwseg[sg][tid];
        swt[tid] = 1.f/s;
    }
    float qv = (tid < 512) ? f_q[b*Dd + tid] : 0.f;
    float p2 = qv*qv;
    #pragma unroll
    for (int off = 32; off >= 1; off >>= 1) p2 += __shfl_xor(p2, off, 64);
    if (lane == 0) redq[wave] = p2;
    __syncthreads();
    {
        int e4 = tid*4;
        float4 s4 = make_float4(0.f,0.f,0.f,0.f);
        #pragma unroll 4
        for (int ns = 0; ns < NCH; ++ns) {
            float4 p = *(const float4*)(ws + WS_PBPART + (size_t)(b*NCH + ns)*(Kk*Dd) + e4);
            s4.x += p.x; s4.y += p.y; s4.z += p.z; s4.w += p.w;
        }
        float sw = swt[e4 >> 9];
        s4.x *= sw; s4.y *= sw; s4.z *= sw; s4.w *= sw;
        *(float4*)&pb[e4] = s4;
        *(float4*)(out_pbg + (size_t)b*Kk*Dd + e4) = s4;
    }
    if (tid < 512) {
        float s = 0.f;
        #pragma unroll
        for (int w = 0; w < 16; ++w) s += redq[w];
        float invq = 1.f/fmaxf(sqrtf(s), NORM_EPS);
        ws[WS_FQN + (size_t)b*Dd + tid] = qv*invq;
    }
    __syncthreads();
    if (tid < 512) {
        int pair = tid >> 3, seg = tid & 7;
        int i = pair >> 3, j = pair & 7;
        float s = 0.f;
        for (int d = seg*64; d < seg*64 + 64; ++d) s += pb[i*Dd + d]*pb[j*Dd + d];
        mseg[pair][seg] = s;
    } else if (tid < 576) {
        int t2 = tid - 512;
        int k = t2 >> 3, sg = t2 & 7;
        float s = 0.f;
        for (int d = sg*64; d < sg*64 + 64; ++d) s += pb[k*Dd + d];
        p1seg[k][sg] = s;
    }
    __syncthreads();
    if (tid < 64) {
        float m = 0.f;
        #pragma unroll
        for (int sg = 0; sg < 8; ++sg) m += mseg[tid][sg];
        ws[WS_M + b*64 + tid] = m;
        if ((tid >> 3) == (tid & 7)) {
            int k = tid & 7;
            ws[WS_IDEN + b*Kk + k] = 1.f/(m + EPSc);
            ws[WS_INP + b*Kk + k] = 1.f/fmaxf(sqrtf(m), NORM_EPS);
        }
    }
    if (tid < 8) {
        float s = 0.f;
        #pragma unroll
        for (int sg = 0; sg < 8; ++sg) s += p1seg[tid][sg];
        ws[WS_P1 + b*Kk + tid] = s;
    }
}

__global__ __launch_bounds__(512, 4) void k5_main(
    const float* __restrict__ f_raw, const int* __restrict__ gt_mask,
    const float* __restrict__ alpha_p, const float* __restrict__ ln_w,
    const float* __restrict__ ln_b, const float* __restrict__ pbg,
    float* __restrict__ ws, float* __restrict__ out_ffg,
    float* __restrict__ out_fbg, float* __restrict__ out_ssem)
{
    int b = blockIdx.x >> 6;
    int chunk = blockIdx.x & 63;
    int tok0 = chunk * 32;
    int tid = threadIdx.x, lane = tid & 63, wave = tid >> 6;
    __shared__ float pls[Kk*Dd];
    __shared__ float scl[32][12];
    __shared__ float Ml[64];
    __shared__ float idenl[8], inpl[8], p1l[8];
    __shared__ float al[8][4];
    __shared__ float swp[8][64];
    for (int e = tid; e < Kk*Dd; e += 512) pls[e] = pbg[(size_t)b*Kk*Dd + e];
    if (tid >= 512-96 && tid < 512-32) Ml[tid-(512-96)] = ws[WS_M + b*64 + (tid-(512-96))];
    else if (tid >= 512-32 && tid < 512-8) {
        int g = (tid-(512-32)) >> 3, k = (tid-(512-32)) & 7;
        if      (g == 0) idenl[k] = ws[WS_IDEN + b*8 + k];
        else if (g == 1) inpl[k]  = ws[WS_INP  + b*8 + k];
        else             p1l[k]   = ws[WS_P1   + b*8 + k];
    }
    __syncthreads();
    int sub = lane >> 4, idx = lane & 15;
    int tokl = wave*4 + sub;
    const float* ftok = f_raw + ((size_t)b*Nn + tok0 + tokl)*Dd;
    float A[8] = {0,0,0,0,0,0,0,0};
    float nf2 = 0.f, sf = 0.f;
    #pragma unroll
    for (int cc = 0; cc < 8; ++cc) {
        int o = cc*64 + idx*4;
        float4 f4 = *(const float4*)(ftok + o);
        #pragma unroll
        for (int k = 0; k < 8; ++k) {
            float4 p4 = *(const float4*)&pls[k*Dd + o];
            A[k] += dot4(f4, p4);
        }
        nf2 += dot4(f4, f4);
        sf  += f4.x + f4.y + f4.z + f4.w;
    }
    #pragma unroll
    for (int m = 1; m <= 8; m <<= 1) {
        #pragma unroll
        for (int k = 0; k < 8; ++k) A[k] += __shfl_xor(A[k], m, 64);
        nf2 += __shfl_xor(nf2, m, 64);
        sf  += __shfl_xor(sf, m, 64);
    }
    float wcsum, wdsum;
    {
        float alpha = alpha_p[0];
        float coef[8], sca = 0.f, sp1 = 0.f;
        #pragma unroll
        for (int k = 0; k < 8; ++k) {
            coef[k] = A[k]*idenl[k];
            sca += coef[k]*A[k];
            sp1 += coef[k]*p1l[k];
        }
        float quad = 0.f;
        #pragma unroll
        for (int i = 0; i < 8; ++i) {
            float ti = 0.f;
            #pragma unroll
            for (int j = 0; j < 8; ++j) ti += Ml[i*8+j]*coef[j];
            quad += coef[i]*ti;
        }
        float sx  = sf - alpha*sp1;
        float sxx = nf2 - 2.f*alpha*sca + alpha*alpha*quad;
        float mu  = sx*(1.f/Dd);
        float var = sxx*(1.f/Dd) - mu*mu;
        float rstd = 1.f/sqrtf(fmaxf(var, 0.f) + LN_EPS);
        float invnf = 1.f/fmaxf(sqrtf(nf2), NORM_EPS);
        float cmin = 1e30f;
        #pragma unroll
        for (int k = 0; k < 8; ++k) cmin = fminf(cmin, 1.f - A[k]*invnf*inpl[k]);
        float invnb = 1.f/fmaxf(sqrtf(quad), NORM_EPS);
        float inb2 = invnb*invnb;
        float gnn = quad*inb2;
        float dloc = gnn*gnn;
        float cp[8];
        #pragma unroll
        for (int k = 0; k < 8; ++k) cp[k] = coef[k]*invnb;
        if (idx == 0) {
            *(float4*)&scl[tokl][0] = make_float4(coef[0],coef[1],coef[2],coef[3]);
            *(float4*)&scl[tokl][4] = make_float4(coef[4],coef[5],coef[6],coef[7]);
            *(float2*)&scl[tokl][8] = make_float2(mu, rstd);
        }
        float spv[4];
        #pragma unroll
        for (int q = 0; q < 4; ++q) {
            int e = idx*4 + q;
            spv[q] = cp[e >> 3]*cp[e & 7];
        }
        #pragma unroll
        for (int q = 0; q < 4; ++q) {
            spv[q] += __shfl_xor(spv[q], 16, 64);
            spv[q] += __shfl_xor(spv[q], 32, 64);
        }
        if (lane < 16)
            *(float4*)&swp[wave][idx*4] = make_float4(spv[0],spv[1],spv[2],spv[3]);
        float cv = (idx == 0) ? cmin : 0.f;
        float dv = (idx == 0) ? dloc : 0.f;
        cv += __shfl_xor(cv, 16, 64); cv += __shfl_xor(cv, 32, 64);
        dv += __shfl_xor(dv, 16, 64); dv += __shfl_xor(dv, 32, 64);
        wcsum = cv; wdsum = dv;
    }
    float alpha = alpha_p[0];
    float ng2h[4], dqh[4];
    {
        int d0 = lane*4;
        float4 pbr[8];
        #pragma unroll
        for (int k = 0; k < 8; ++k) pbr[k] = *(const float4*)&pls[k*Dd + d0];
        float4 w4 = *(const float4*)(ln_w + d0);
        float4 b4 = *(const float4*)(ln_b + d0);
        float4 q4 = *(const float4*)(ws + WS_FQN + b*Dd + d0);
        #pragma unroll
        for (int t = 0; t < 4; ++t) {
            int lt = wave*4 + t;
            float4 cA = *(const float4*)&scl[lt][0];
            float4 cB = *(const float4*)&scl[lt][4];
            float2 mr = *(const float2*)&scl[lt][8];
            size_t rowoff = ((size_t)b*Nn + tok0 + lt)*Dd;
            float4 fv = *(const float4*)(f_raw + rowoff + d0);
            float4 fb;
            fb.x = cA.x*pbr[0].x + cA.y*pbr[1].x + cA.z*pbr[2].x + cA.w*pbr[3].x
                 + cB.x*pbr[4].x + cB.y*pbr[5].x + cB.z*pbr[6].x + cB.w*pbr[7].x;
            fb.y = cA.x*pbr[0].y + cA.y*pbr[1].y + cA.z*pbr[2].y + cA.w*pbr[3].y
                 + cB.x*pbr[4].y + cB.y*pbr[5].y + cB.z*pbr[6].y + cB.w*pbr[7].y;
            fb.z = cA.x*pbr[0].z + cA.y*pbr[1].z + cA.z*pbr[2].z + cA.w*pbr[3].z
                 + cB.x*pbr[4].z + cB.y*pbr[5].z + cB.z*pbr[6].z + cB.w*pbr[7].z;
            fb.w = cA.x*pbr[0].w + cA.y*pbr[1].w + cA.z*pbr[2].w + cA.w*pbr[3].w
                 + cB.x*pbr[4].w + cB.y*pbr[5].w + cB.z*pbr[6].w + cB.w*pbr[7].w;
            nt_store4(out_fbg + rowoff + d0, fb);
            float4 g;
            g.x = (fv.x - alpha*fb.x - mr.x)*mr.y*w4.x + b4.x;
            g.y = (fv.y - alpha*fb.y - mr.x)*mr.y*w4.y + b4.y;
            g.z = (fv.z - alpha*fb.z - mr.x)*mr.y*w4.z + b4.z;
            g.w = (fv.w - alpha*fb.w - mr.x)*mr.y*w4.w + b4.w;
            nt_store4(out_ffg + rowoff + d0, g);
            ng2h[t] = dot4(g, g);
            dqh[t]  = dot4(g, q4);
        }
    }
    float align_s = 0.f, align_c = 0.f;
    {
        int d0 = 256 + lane*4;
        float4 pbr[8];
        #pragma unroll
        for (int k = 0; k < 8; ++k) pbr[k] = *(const float4*)&pls[k*Dd + d0];
        float4 w4 = *(const float4*)(ln_w + d0);
        float4 b4 = *(const float4*)(ln_b + d0);
        float4 q4 = *(const float4*)(ws + WS_FQN + b*Dd + d0);
        #pragma unroll
        for (int t = 0; t < 4; ++t) {
            int lt = wave*4 + t;
            size_t n = (size_t)b*Nn + tok0 + lt;
            float4 cA = *(const float4*)&scl[lt][0];
            float4 cB = *(const float4*)&scl[lt][4];
            float2 mr = *(const float2*)&scl[lt][8];
            size_t rowoff = n*(size_t)Dd;
            float4 fv = *(const float4*)(f_raw + rowoff + d0);
            float4 fb;
            fb.x = cA.x*pbr[0].x + cA.y*pbr[1].x + cA.z*pbr[2].x + cA.w*pbr[3].x
                 + cB.x*pbr[4].x + cB.y*pbr[5].x + cB.z*pbr[6].x + cB.w*pbr[7].x;
            fb.y = cA.x*pbr[0].y + cA.y*pbr[1].y + cA.z*pbr[2].y + cA.w*pbr[3].y
                 + cB.x*pbr[4].y + cB.y*pbr[5].y + cB.z*pbr[6].y + cB.w*pbr[7].y;
            fb.z = cA.x*pbr[0].z + cA.y*pbr[1].z + cA.z*pbr[2].z + cA.w*pbr[3].z
                 + cB.x*pbr[4].z + cB.y*pbr[5].z + cB.z*pbr[6].z + cB.w*pbr[7].z;
            fb.w = cA.x*pbr[0].w + cA.y*pbr[1].w + cA.z*pbr[2].w + cA.w*pbr[3].w
                 + cB.x*pbr[4].w + cB.y*pbr[5].w + cB.z*pbr[6].w + cB.w*pbr[7].w;
            nt_store4(out_fbg + rowoff + d0, fb);
            float4 g;
            g.x = (fv.x - alpha*fb.x - mr.x)*mr.y*w4.x + b4.x;
            g.y = (fv.y - alpha*fb.y - mr.x)*mr.y*w4.y + b4.y;
            g.z = (fv.z - alpha*fb.z - mr.x)*mr.y*w4.z + b4.z;
            g.w = (fv.w - alpha*fb.w - mr.x)*mr.y*w4.w + b4.w;
            nt_store4(out_ffg + rowoff + d0, g);
            float ng2 = ng2h[t] + dot4(g, g);
            float dq  = dqh[t]  + dot4(g, q4);
            #pragma unroll
            for (int off = 32; off >= 1; off >>= 1) {
                ng2 += __shfl_xor(ng2, off, 64);
                dq  += __shfl_xor(dq,  off, 64);
            }
            float sim = dq * (1.f/fmaxf(sqrtf(ng2), NORM_EPS));
            float ssem = 1.f/(1.f + expf(-sim*(1.f/TAU)));
            if (lane == 0) {
                out_ssem[n] = ssem;
                if (gt_mask[n] != 0) { align_s += -logf(fmaxf(ssem, EPSc)); align_c += 1.f; }
            }
        }
    }
    if (lane == 0) {
        al[wave][0] = align_s; al[wave][1] = align_c;
        al[wave][2] = wcsum;   al[wave][3] = wdsum;
    }
    __syncthreads();
    if (tid < 64) {
        float s = 0.f;
        #pragma unroll
        for (int w = 0; w < 8; ++w) s += swp[w][tid];
        ws[WS_SP + (size_t)blockIdx.x*64 + tid] = s;
    }
    if (tid == 0) {
        float as = 0.f, ac = 0.f, cs = 0.f, ds = 0.f;
        #pragma unroll
        for (int w = 0; w < 8; ++w) {
            as += al[w][0]; ac += al[w][1]; cs += al[w][2]; ds += al[w][3];
        }
        ws[WS_P5B + (size_t)blockIdx.x*2 + 0] = as;
        ws[WS_P5B + (size_t)blockIdx.x*2 + 1] = ac;
        ws[WS_P5A + (size_t)blockIdx.x*2 + 0] = cs;
        ws[WS_P5A + (size_t)blockIdx.x*2 + 1] = ds;
    }
}

__global__ __launch_bounds__(1024) void k8_final(const float* __restrict__ ws,
                                                 float* __restrict__ out_loss) {
    int tid = threadIdx.x, lane = tid & 63, wave = tid >> 6;
    __shared__ float Sf[Bb][64];
    __shared__ float Mf[Bb][64];
    __shared__ float Af[Bb][64];
    __shared__ float trb[Bb];
    __shared__ double redd[16][4];
    int b = tid >> 6, e = tid & 63;
    float s = 0.f;
    #pragma unroll 8
    for (int c = 0; c < NCH; ++c)
        s += ws[WS_SP + (size_t)(b*NCH + c)*64 + e];
    Sf[b][e] = s;
    Mf[b][e] = ws[WS_M + b*64 + e];
    __syncthreads();
    {
        int ii = e >> 3, jj = e & 7;
        float a = 0.f;
        #pragma unroll
        for (int k = 0; k < 8; ++k) a += Mf[b][ii*8+k]*Sf[b][k*8+jj];
        Af[b][e] = a;
    }
    __syncthreads();
    {
        float p = Af[b][e]*Af[b][(e & 7)*8 + (e >> 3)];
        #pragma unroll
        for (int off = 32; off >= 1; off >>= 1) p += __shfl_xor(p, off, 64);
        if (lane == 0) trb[b] = p;
    }
    double c  = (double)ws[WS_P5A + (size_t)tid*2 + 0];
    double dg = (double)ws[WS_P5A + (size_t)tid*2 + 1];
    double as = (double)ws[WS_P5B + (size_t)tid*2 + 0];
    double ac = (double)ws[WS_P5B + (size_t)tid*2 + 1];
    #pragma unroll
    for (int off = 32; off >= 1; off >>= 1) {
        c  += __shfl_xor(c,  off, 64);
        dg += __shfl_xor(dg, off, 64);
        as += __shfl_xor(as, off, 64);
        ac += __shfl_xor(ac, off, 64);
    }
    if (lane == 0) { redd[wave][0]=c; redd[wave][1]=dg; redd[wave][2]=as; redd[wave][3]=ac; }
    __syncthreads();
    if (tid == 0) {
        double ct=0, dgt=0, ast=0, act=0, trt=0;
        for (int w = 0; w < 16; ++w) {
            ct += redd[w][0]; dgt += redd[w][1]; ast += redd[w][2]; act += redd[w][3];
        }
        for (int bb = 0; bb < Bb; ++bb) trt += (double)trb[bb];
        out_loss[0] = (float)(ct / (double)((size_t)Bb*Nn));
        out_loss[1] = (float)((trt - dgt) / ((double)Bb*(double)Nn*(double)Nn));
        out_loss[2] = (float)(act > 0.0 ? ast / (act > 1.0 ? act : 1.0) : 0.0);
    }
}

extern "C" void kernel_launch(void* const* d_in, const int* in_sizes, int n_in,
                              void* d_out, int out_size, void* d_ws, size_t ws_size,
                              hipStream_t stream) {
    (void)in_sizes; (void)n_in; (void)out_size; (void)ws_size;
    const float* f_raw   = (const float*)d_in[0];
    const float* f_q     = (const float*)d_in[1];
    const int*   gt_mask = (const int*)d_in[2];
    const float* q_bg    = (const float*)d_in[3];
    const float* alpha   = (const float*)d_in[4];
    const float* ln_w    = (const float*)d_in[5];
    const float* ln_b    = (const float*)d_in[6];
    float* out = (float*)d_out;
    float* wsp = (float*)d_ws;

    void* args[] = { (void*)&f_raw, (void*)&f_q, (void*)&gt_mask, (void*)&q_bg,
                     (void*)&alpha, (void*)&ln_w, (void*)&ln_b, (void*)&out, (void*)&wsp };
    hipError_t err = hipLaunchCooperativeKernel((void*)mega_kernel, dim3(512), dim3(512),
                                                args, 0, stream);
    if (err != hipSuccess) {
        // fallback: proven 4-kernel path
        k1_scores<<<Bb*NCH, 512, 0, stream>>>(f_raw, q_bg, wsp);
        k3b_all<<<Bb, 1024, 0, stream>>>(wsp, out + OUT_PBG, f_q);
        k5_main<<<Bb*NCH, 512, 0, stream>>>(f_raw, gt_mask, alpha, ln_w, ln_b,
                                            out + OUT_PBG, wsp,
                                            out + OUT_FFG, out + OUT_FBG, out + OUT_SSEM);
        k8_final<<<1, 1024, 0, stream>>>(wsp, out + OUT_LOSS);
    }
}

// Round 17
// 102.734 us; speedup vs baseline: 5.5361x; 5.5361x over previous
//
#include <hip/hip_runtime.h>
#include <math.h>

#define Bb 16
#define Nn 2048
#define Dd 512
#define Kk 8

constexpr float TAU = 0.07f;
constexpr float EPSc = 1e-6f;
constexpr float LN_EPS = 1e-5f;
constexpr float NORM_EPS = 1e-12f;
constexpr float SCALE = 0.04419417382415922f; // 1/sqrt(512)

// output layout (floats)
constexpr size_t OUT_FFG  = 0;
constexpr size_t OUT_FBG  = (size_t)Bb*Nn*Dd;
constexpr size_t OUT_PBG  = OUT_FBG + (size_t)Bb*Nn*Dd;
constexpr size_t OUT_SSEM = OUT_PBG + (size_t)Bb*Kk*Dd;
constexpr size_t OUT_LOSS = OUT_SSEM + (size_t)Bb*Nn;

// ws layout (floats)
constexpr int    NCH = 64;                                      // chunks of 32 tokens
constexpr size_t WS_PBPART = 0;                                 // B*NCH*K*D = 4M
constexpr size_t WS_SUMW   = WS_PBPART + (size_t)Bb*NCH*Kk*Dd;  // B*NCH*8
constexpr size_t WS_M      = WS_SUMW + (size_t)Bb*NCH*Kk;       // B*64
constexpr size_t WS_IDEN   = WS_M + Bb*64;                      // B*K
constexpr size_t WS_INP    = WS_IDEN + Bb*Kk;                   // B*K
constexpr size_t WS_P1     = WS_INP + Bb*Kk;                    // B*K
constexpr size_t WS_FQN    = WS_P1 + Bb*Kk;                     // B*D
constexpr size_t WS_SP     = WS_FQN + (size_t)Bb*Dd;            // B*NCH*64 = 65536
constexpr size_t WS_P5A    = WS_SP + (size_t)Bb*NCH*64;         // 1024*2
constexpr size_t WS_P5B    = WS_P5A + 2048;                     // 1024*2

__device__ __forceinline__ float dot4(float4 a, float4 b) {
    return a.x*b.x + a.y*b.y + a.z*b.z + a.w*b.w;
}

using f32x4 = __attribute__((ext_vector_type(4))) float;
__device__ __forceinline__ void nt_store4(float* p, float4 v) {
    f32x4 t; t.x = v.x; t.y = v.y; t.z = v.z; t.w = v.w;
    __builtin_nontemporal_store(t, (f32x4*)p);
}

// ============ K1: coalesced dots + exp + p~ partials (32 tok/block, 8 waves) ============
__global__ __launch_bounds__(512, 4) void k1_scores(const float* __restrict__ f_raw,
                                                    const float* __restrict__ q_bg,
                                                    float* __restrict__ ws) {
    int b = blockIdx.x >> 6;
    int chunk = blockIdx.x & 63;
    int tok0 = chunk * 32;
    int tid = threadIdx.x, lane = tid & 63, wave = tid >> 6;   // 8 waves
    __shared__ float qls[Kk*Dd];          // 16 KB
    __shared__ float wlds[32][8];         // 1 KB
    __shared__ float swsum[8][8];
    for (int e = tid; e < Kk*Dd; e += 512) qls[e] = q_bg[e];
    __syncthreads();
    int sub = lane >> 4, idx = lane & 15;
    int tokl = wave*4 + sub;              // wave owns tokens wave*4..+3
    const float* ftok = f_raw + ((size_t)b*Nn + tok0 + tokl)*Dd;

    float a[8] = {0,0,0,0,0,0,0,0};
    #pragma unroll
    for (int cc = 0; cc < 8; ++cc) {
        int o = cc*64 + idx*4;
        float4 f4 = *(const float4*)(ftok + o);
        #pragma unroll
        for (int k = 0; k < 8; ++k) {
            float4 q4 = *(const float4*)&qls[k*Dd + o];
            a[k] += dot4(f4, q4);
        }
    }
    #pragma unroll
    for (int m = 1; m <= 8; m <<= 1) {
        #pragma unroll
        for (int k = 0; k < 8; ++k) a[k] += __shfl_xor(a[k], m, 64);
    }
    float w8[8];
    #pragma unroll
    for (int k = 0; k < 8; ++k) w8[k] = expf(a[k]*SCALE);
    if (idx == 0) {
        *(float4*)&wlds[tokl][0] = make_float4(w8[0],w8[1],w8[2],w8[3]);
        *(float4*)&wlds[tokl][4] = make_float4(w8[4],w8[5],w8[6],w8[7]);
    }
    float sw[8];
    #pragma unroll
    for (int k = 0; k < 8; ++k) sw[k] = (idx == 0) ? w8[k] : 0.f;
    #pragma unroll
    for (int k = 0; k < 8; ++k) {
        sw[k] += __shfl_xor(sw[k], 16, 64);
        sw[k] += __shfl_xor(sw[k], 32, 64);
    }
    if (lane == 0) {
        *(float4*)&swsum[wave][0] = make_float4(sw[0],sw[1],sw[2],sw[3]);
        *(float4*)&swsum[wave][4] = make_float4(sw[4],sw[5],sw[6],sw[7]);
    }
    __syncthreads();   // wlds + swsum ready
    if (tid < 8) {
        float s = 0.f;
        #pragma unroll
        for (int w = 0; w < 8; ++w) s += swsum[w][tid];
        ws[WS_SUMW + (size_t)(b*NCH + chunk)*8 + tid] = s;
    }
    // phase B: p~ partials; thread -> d (0..511), loop 32 tokens
    int d = tid;
    const float* fcol = f_raw + ((size_t)b*Nn + tok0)*Dd + d;
    float acc[8] = {0,0,0,0,0,0,0,0};
    #pragma unroll 4
    for (int nn = 0; nn < 32; ++nn) {
        float f = fcol[(size_t)nn*Dd];
        float4 wa = *(const float4*)&wlds[nn][0];
        float4 wb = *(const float4*)&wlds[nn][4];
        acc[0]+=wa.x*f; acc[1]+=wa.y*f; acc[2]+=wa.z*f; acc[3]+=wa.w*f;
        acc[4]+=wb.x*f; acc[5]+=wb.y*f; acc[6]+=wb.z*f; acc[7]+=wb.w*f;
    }
    #pragma unroll
    for (int k = 0; k < 8; ++k)
        ws[WS_PBPART + ((size_t)(b*NCH + chunk)*8 + k)*Dd + d] = acc[k];
}

// ============ K3b: merged reduce + stats (16 blocks x 1024) ============
__global__ __launch_bounds__(1024) void k3b_all(float* __restrict__ ws,
                                                float* __restrict__ out_pbg,
                                                const float* __restrict__ f_q) {
    int b = blockIdx.x, tid = threadIdx.x;
    int lane = tid & 63, wave = tid >> 6;   // 16 waves
    __shared__ float pb[Kk*Dd];
    __shared__ float swt[8];
    __shared__ float sumwseg[8][8];
    __shared__ float redq[16];
    __shared__ float mseg[64][8];
    __shared__ float p1seg[8][8];
    if (tid < 64) {
        int k = tid & 7, sg = tid >> 3;
        float s = 0.f;
        #pragma unroll
        for (int i = 0; i < 8; ++i)
            s += ws[WS_SUMW + (size_t)(b*NCH + sg*8 + i)*8 + k];
        sumwseg[sg][k] = s;
    }
    __syncthreads();
    if (tid < 8) {
        float s = 0.f;
        #pragma unroll
        for (int sg = 0; sg < 8; ++sg) s += sumwseg[sg][tid];
        swt[tid] = 1.f/s;
    }
    // f_q norm partial (all 16 waves; waves >=8 contribute 0)
    float qv = (tid < 512) ? f_q[b*Dd + tid] : 0.f;
    float p2 = qv*qv;
    #pragma unroll
    for (int off = 32; off >= 1; off >>= 1) p2 += __shfl_xor(p2, off, 64);
    if (lane == 0) redq[wave] = p2;
    __syncthreads();   // swt + redq ready
    // p_bg reduce: thread handles e4 = tid*4
    {
        int e4 = tid*4;
        float4 s4 = make_float4(0.f,0.f,0.f,0.f);
        #pragma unroll 4
        for (int ns = 0; ns < NCH; ++ns) {
            float4 p = *(const float4*)(ws + WS_PBPART + (size_t)(b*NCH + ns)*(Kk*Dd) + e4);
            s4.x += p.x; s4.y += p.y; s4.z += p.z; s4.w += p.w;
        }
        float sw = swt[e4 >> 9];
        s4.x *= sw; s4.y *= sw; s4.z *= sw; s4.w *= sw;
        *(float4*)&pb[e4] = s4;
        *(float4*)(out_pbg + (size_t)b*Kk*Dd + e4) = s4;
    }
    if (tid < 512) {
        float s = 0.f;
        #pragma unroll
        for (int w = 0; w < 16; ++w) s += redq[w];
        float invq = 1.f/fmaxf(sqrtf(s), NORM_EPS);
        ws[WS_FQN + (size_t)b*Dd + tid] = qv*invq;
    }
    __syncthreads();   // pb ready
    if (tid < 512) {
        int pair = tid >> 3, seg = tid & 7;
        int i = pair >> 3, j = pair & 7;
        float s = 0.f;
        for (int d = seg*64; d < seg*64 + 64; ++d) s += pb[i*Dd + d]*pb[j*Dd + d];
        mseg[pair][seg] = s;
    } else if (tid < 576) {
        int t2 = tid - 512;
        int k = t2 >> 3, sg = t2 & 7;
        float s = 0.f;
        for (int d = sg*64; d < sg*64 + 64; ++d) s += pb[k*Dd + d];
        p1seg[k][sg] = s;
    }
    __syncthreads();
    if (tid < 64) {
        float m = 0.f;
        #pragma unroll
        for (int sg = 0; sg < 8; ++sg) m += mseg[tid][sg];
        ws[WS_M + b*64 + tid] = m;
        if ((tid >> 3) == (tid & 7)) {
            int k = tid & 7;
            ws[WS_IDEN + b*Kk + k] = 1.f/(m + EPSc);
            ws[WS_INP + b*Kk + k] = 1.f/fmaxf(sqrtf(m), NORM_EPS);
        }
    }
    if (tid < 8) {
        float s = 0.f;
        #pragma unroll
        for (int sg = 0; sg < 8; ++sg) s += p1seg[tid][sg];
        ws[WS_P1 + b*Kk + tid] = s;
    }
}

// ============ K5: coalesced dots -> group scalars (+S partials) -> stream ============
__global__ __launch_bounds__(512, 4) void k5_main(
    const float* __restrict__ f_raw, const int* __restrict__ gt_mask,
    const float* __restrict__ alpha_p, const float* __restrict__ ln_w,
    const float* __restrict__ ln_b, const float* __restrict__ pbg,
    float* __restrict__ ws, float* __restrict__ out_ffg,
    float* __restrict__ out_fbg, float* __restrict__ out_ssem)
{
    int b = blockIdx.x >> 6;
    int chunk = blockIdx.x & 63;
    int tok0 = chunk * 32;
    int tid = threadIdx.x, lane = tid & 63, wave = tid >> 6;   // 8 waves
    __shared__ float pls[Kk*Dd];         // 16 KB
    __shared__ float scl[32][12];
    __shared__ float Ml[64];
    __shared__ float idenl[8], inpl[8], p1l[8];
    __shared__ float al[8][4];
    __shared__ float swp[8][64];         // 2 KB S partials
    for (int e = tid; e < Kk*Dd; e += 512) pls[e] = pbg[(size_t)b*Kk*Dd + e];
    if (tid >= 512-96 && tid < 512-32) Ml[tid-(512-96)] = ws[WS_M + b*64 + (tid-(512-96))];
    else if (tid >= 512-32 && tid < 512-8) {
        int g = (tid-(512-32)) >> 3, k = (tid-(512-32)) & 7;
        if      (g == 0) idenl[k] = ws[WS_IDEN + b*8 + k];
        else if (g == 1) inpl[k]  = ws[WS_INP  + b*8 + k];
        else             p1l[k]   = ws[WS_P1   + b*8 + k];
    }
    __syncthreads();
    int sub = lane >> 4, idx = lane & 15;
    int tokl = wave*4 + sub;              // wave owns tokens wave*4..+3
    const float* ftok = f_raw + ((size_t)b*Nn + tok0 + tokl)*Dd;

    float A[8] = {0,0,0,0,0,0,0,0};
    float nf2 = 0.f, sf = 0.f;
    #pragma unroll
    for (int cc = 0; cc < 8; ++cc) {
        int o = cc*64 + idx*4;
        float4 f4 = *(const float4*)(ftok + o);
        #pragma unroll
        for (int k = 0; k < 8; ++k) {
            float4 p4 = *(const float4*)&pls[k*Dd + o];
            A[k] += dot4(f4, p4);
        }
        nf2 += dot4(f4, f4);
        sf  += f4.x + f4.y + f4.z + f4.w;
    }
    #pragma unroll
    for (int m = 1; m <= 8; m <<= 1) {
        #pragma unroll
        for (int k = 0; k < 8; ++k) A[k] += __shfl_xor(A[k], m, 64);
        nf2 += __shfl_xor(nf2, m, 64);
        sf  += __shfl_xor(sf, m, 64);
    }
    // group-local scalar section (16 lanes redundant per token)
    float wcsum, wdsum;
    {
        float alpha = alpha_p[0];
        float coef[8], sca = 0.f, sp1 = 0.f;
        #pragma unroll
        for (int k = 0; k < 8; ++k) {
            coef[k] = A[k]*idenl[k];
            sca += coef[k]*A[k];
            sp1 += coef[k]*p1l[k];
        }
        float quad = 0.f;
        #pragma unroll
        for (int i = 0; i < 8; ++i) {
            float ti = 0.f;
            #pragma unroll
            for (int j = 0; j < 8; ++j) ti += Ml[i*8+j]*coef[j];
            quad += coef[i]*ti;
        }
        float sx  = sf - alpha*sp1;
        float sxx = nf2 - 2.f*alpha*sca + alpha*alpha*quad;
        float mu  = sx*(1.f/Dd);
        float var = sxx*(1.f/Dd) - mu*mu;
        float rstd = 1.f/sqrtf(fmaxf(var, 0.f) + LN_EPS);
        float invnf = 1.f/fmaxf(sqrtf(nf2), NORM_EPS);
        float cmin = 1e30f;
        #pragma unroll
        for (int k = 0; k < 8; ++k) cmin = fminf(cmin, 1.f - A[k]*invnf*inpl[k]);
        float invnb = 1.f/fmaxf(sqrtf(quad), NORM_EPS);
        float inb2 = invnb*invnb;
        float gnn = quad*inb2;
        float dloc = gnn*gnn;
        float cp[8];
        #pragma unroll
        for (int k = 0; k < 8; ++k) cp[k] = coef[k]*invnb;
        if (idx == 0) {
            *(float4*)&scl[tokl][0] = make_float4(coef[0],coef[1],coef[2],coef[3]);
            *(float4*)&scl[tokl][4] = make_float4(coef[4],coef[5],coef[6],coef[7]);
            *(float2*)&scl[tokl][8] = make_float2(mu, rstd);
        }
        // S partials: lane idx owns entries idx*4..+3 of the 8x8 outer product
        float spv[4];
        #pragma unroll
        for (int q = 0; q < 4; ++q) {
            int e = idx*4 + q;
            spv[q] = cp[e >> 3]*cp[e & 7];
        }
        #pragma unroll
        for (int q = 0; q < 4; ++q) {
            spv[q] += __shfl_xor(spv[q], 16, 64);
            spv[q] += __shfl_xor(spv[q], 32, 64);
        }
        if (lane < 16)
            *(float4*)&swp[wave][idx*4] = make_float4(spv[0],spv[1],spv[2],spv[3]);
        float cv = (idx == 0) ? cmin : 0.f;
        float dv = (idx == 0) ? dloc : 0.f;
        cv += __shfl_xor(cv, 16, 64); cv += __shfl_xor(cv, 32, 64);
        dv += __shfl_xor(dv, 16, 64); dv += __shfl_xor(dv, 32, 64);
        wcsum = cv; wdsum = dv;
    }
    // phase B: stream; NO barrier — scl written by this wave; 4 tokens/wave
    float alpha = alpha_p[0];
    float ng2h[4], dqh[4];
    {
        int d0 = lane*4;
        float4 pbr[8];
        #pragma unroll
        for (int k = 0; k < 8; ++k) pbr[k] = *(const float4*)&pls[k*Dd + d0];
        float4 w4 = *(const float4*)(ln_w + d0);
        float4 b4 = *(const float4*)(ln_b + d0);
        float4 q4 = *(const float4*)(ws + WS_FQN + b*Dd + d0);
        #pragma unroll
        for (int t = 0; t < 4; ++t) {
            int lt = wave*4 + t;
            float4 cA = *(const float4*)&scl[lt][0];
            float4 cB = *(const float4*)&scl[lt][4];
            float2 mr = *(const float2*)&scl[lt][8];
            size_t rowoff = ((size_t)b*Nn + tok0 + lt)*Dd;
            float4 fv = *(const float4*)(f_raw + rowoff + d0);
            float4 fb;
            fb.x = cA.x*pbr[0].x + cA.y*pbr[1].x + cA.z*pbr[2].x + cA.w*pbr[3].x
                 + cB.x*pbr[4].x + cB.y*pbr[5].x + cB.z*pbr[6].x + cB.w*pbr[7].x;
            fb.y = cA.x*pbr[0].y + cA.y*pbr[1].y + cA.z*pbr[2].y + cA.w*pbr[3].y
                 + cB.x*pbr[4].y + cB.y*pbr[5].y + cB.z*pbr[6].y + cB.w*pbr[7].y;
            fb.z = cA.x*pbr[0].z + cA.y*pbr[1].z + cA.z*pbr[2].z + cA.w*pbr[3].z
                 + cB.x*pbr[4].z + cB.y*pbr[5].z + cB.z*pbr[6].z + cB.w*pbr[7].z;
            fb.w = cA.x*pbr[0].w + cA.y*pbr[1].w + cA.z*pbr[2].w + cA.w*pbr[3].w
                 + cB.x*pbr[4].w + cB.y*pbr[5].w + cB.z*pbr[6].w + cB.w*pbr[7].w;
            nt_store4(out_fbg + rowoff + d0, fb);
            float4 g;
            g.x = (fv.x - alpha*fb.x - mr.x)*mr.y*w4.x + b4.x;
            g.y = (fv.y - alpha*fb.y - mr.x)*mr.y*w4.y + b4.y;
            g.z = (fv.z - alpha*fb.z - mr.x)*mr.y*w4.z + b4.z;
            g.w = (fv.w - alpha*fb.w - mr.x)*mr.y*w4.w + b4.w;
            nt_store4(out_ffg + rowoff + d0, g);
            ng2h[t] = dot4(g, g);
            dqh[t]  = dot4(g, q4);
        }
    }
    float align_s = 0.f, align_c = 0.f;
    {
        int d0 = 256 + lane*4;
        float4 pbr[8];
        #pragma unroll
        for (int k = 0; k < 8; ++k) pbr[k] = *(const float4*)&pls[k*Dd + d0];
        float4 w4 = *(const float4*)(ln_w + d0);
        float4 b4 = *(const float4*)(ln_b + d0);
        float4 q4 = *(const float4*)(ws + WS_FQN + b*Dd + d0);
        #pragma unroll
        for (int t = 0; t < 4; ++t) {
            int lt = wave*4 + t;
            size_t n = (size_t)b*Nn + tok0 + lt;
            float4 cA = *(const float4*)&scl[lt][0];
            float4 cB = *(const float4*)&scl[lt][4];
            float2 mr = *(const float2*)&scl[lt][8];
            size_t rowoff = n*(size_t)Dd;
            float4 fv = *(const float4*)(f_raw + rowoff + d0);
            float4 fb;
            fb.x = cA.x*pbr[0].x + cA.y*pbr[1].x + cA.z*pbr[2].x + cA.w*pbr[3].x
                 + cB.x*pbr[4].x + cB.y*pbr[5].x + cB.z*pbr[6].x + cB.w*pbr[7].x;
            fb.y = cA.x*pbr[0].y + cA.y*pbr[1].y + cA.z*pbr[2].y + cA.w*pbr[3].y
                 + cB.x*pbr[4].y + cB.y*pbr[5].y + cB.z*pbr[6].y + cB.w*pbr[7].y;
            fb.z = cA.x*pbr[0].z + cA.y*pbr[1].z + cA.z*pbr[2].z + cA.w*pbr[3].z
                 + cB.x*pbr[4].z + cB.y*pbr[5].z + cB.z*pbr[6].z + cB.w*pbr[7].z;
            fb.w = cA.x*pbr[0].w + cA.y*pbr[1].w + cA.z*pbr[2].w + cA.w*pbr[3].w
                 + cB.x*pbr[4].w + cB.y*pbr[5].w + cB.z*pbr[6].w + cB.w*pbr[7].w;
            nt_store4(out_fbg + rowoff + d0, fb);
            float4 g;
            g.x = (fv.x - alpha*fb.x - mr.x)*mr.y*w4.x + b4.x;
            g.y = (fv.y - alpha*fb.y - mr.x)*mr.y*w4.y + b4.y;
            g.z = (fv.z - alpha*fb.z - mr.x)*mr.y*w4.z + b4.z;
            g.w = (fv.w - alpha*fb.w - mr.x)*mr.y*w4.w + b4.w;
            nt_store4(out_ffg + rowoff + d0, g);
            float ng2 = ng2h[t] + dot4(g, g);
            float dq  = dqh[t]  + dot4(g, q4);
            #pragma unroll
            for (int off = 32; off >= 1; off >>= 1) {
                ng2 += __shfl_xor(ng2, off, 64);
                dq  += __shfl_xor(dq,  off, 64);
            }
            float sim = dq * (1.f/fmaxf(sqrtf(ng2), NORM_EPS));
            float ssem = 1.f/(1.f + expf(-sim*(1.f/TAU)));
            if (lane == 0) {
                out_ssem[n] = ssem;
                if (gt_mask[n] != 0) { align_s += -logf(fmaxf(ssem, EPSc)); align_c += 1.f; }
            }
        }
    }
    if (lane == 0) {
        al[wave][0] = align_s; al[wave][1] = align_c;
        al[wave][2] = wcsum;   al[wave][3] = wdsum;
    }
    __syncthreads();
    if (tid < 64) {
        float s = 0.f;
        #pragma unroll
        for (int w = 0; w < 8; ++w) s += swp[w][tid];
        ws[WS_SP + (size_t)blockIdx.x*64 + tid] = s;
    }
    if (tid == 0) {
        float as = 0.f, ac = 0.f, cs = 0.f, ds = 0.f;
        #pragma unroll
        for (int w = 0; w < 8; ++w) {
            as += al[w][0]; ac += al[w][1]; cs += al[w][2]; ds += al[w][3];
        }
        ws[WS_P5B + (size_t)blockIdx.x*2 + 0] = as;
        ws[WS_P5B + (size_t)blockIdx.x*2 + 1] = ac;
        ws[WS_P5A + (size_t)blockIdx.x*2 + 0] = cs;
        ws[WS_P5A + (size_t)blockIdx.x*2 + 1] = ds;
    }
}

// ============ K8: merged gram trace + losses (1 block x 1024) ============
__global__ __launch_bounds__(1024) void k8_final(const float* __restrict__ ws,
                                                 float* __restrict__ out_loss) {
    int tid = threadIdx.x, lane = tid & 63, wave = tid >> 6;   // 16 waves
    __shared__ float Sf[Bb][64];
    __shared__ float Mf[Bb][64];
    __shared__ float Af[Bb][64];
    __shared__ float trb[Bb];
    __shared__ double redd[16][4];
    int b = tid >> 6, e = tid & 63;     // wave == b, lane == e
    float s = 0.f;
    #pragma unroll 8
    for (int c = 0; c < NCH; ++c)
        s += ws[WS_SP + (size_t)(b*NCH + c)*64 + e];
    Sf[b][e] = s;
    Mf[b][e] = ws[WS_M + b*64 + e];
    __syncthreads();
    {
        int ii = e >> 3, jj = e & 7;
        float a = 0.f;
        #pragma unroll
        for (int k = 0; k < 8; ++k) a += Mf[b][ii*8+k]*Sf[b][k*8+jj];
        Af[b][e] = a;
    }
    __syncthreads();
    {
        float p = Af[b][e]*Af[b][(e & 7)*8 + (e >> 3)];
        #pragma unroll
        for (int off = 32; off >= 1; off >>= 1) p += __shfl_xor(p, off, 64);
        if (lane == 0) trb[b] = p;
    }
    // losses: 1024 blocks of P5A/P5B, one per thread
    double c  = (double)ws[WS_P5A + (size_t)tid*2 + 0];
    double dg = (double)ws[WS_P5A + (size_t)tid*2 + 1];
    double as = (double)ws[WS_P5B + (size_t)tid*2 + 0];
    double ac = (double)ws[WS_P5B + (size_t)tid*2 + 1];
    #pragma unroll
    for (int off = 32; off >= 1; off >>= 1) {
        c  += __shfl_xor(c,  off, 64);
        dg += __shfl_xor(dg, off, 64);
        as += __shfl_xor(as, off, 64);
        ac += __shfl_xor(ac, off, 64);
    }
    if (lane == 0) { redd[wave][0]=c; redd[wave][1]=dg; redd[wave][2]=as; redd[wave][3]=ac; }
    __syncthreads();
    if (tid == 0) {
        double ct=0, dgt=0, ast=0, act=0, trt=0;
        for (int w = 0; w < 16; ++w) {
            ct += redd[w][0]; dgt += redd[w][1]; ast += redd[w][2]; act += redd[w][3];
        }
        for (int bb = 0; bb < Bb; ++bb) trt += (double)trb[bb];
        out_loss[0] = (float)(ct / (double)((size_t)Bb*Nn));
        out_loss[1] = (float)((trt - dgt) / ((double)Bb*(double)Nn*(double)Nn));
        out_loss[2] = (float)(act > 0.0 ? ast / (act > 1.0 ? act : 1.0) : 0.0);
    }
}

extern "C" void kernel_launch(void* const* d_in, const int* in_sizes, int n_in,
                              void* d_out, int out_size, void* d_ws, size_t ws_size,
                              hipStream_t stream) {
    (void)in_sizes; (void)n_in; (void)out_size; (void)ws_size;
    const float* f_raw   = (const float*)d_in[0];
    const float* f_q     = (const float*)d_in[1];
    const int*   gt_mask = (const int*)d_in[2];
    const float* q_bg    = (const float*)d_in[3];
    const float* alpha   = (const float*)d_in[4];
    const float* ln_w    = (const float*)d_in[5];
    const float* ln_b    = (const float*)d_in[6];
    float* out = (float*)d_out;
    float* ws  = (float*)d_ws;

    k1_scores<<<Bb*NCH, 512, 0, stream>>>(f_raw, q_bg, ws);
    k3b_all<<<Bb, 1024, 0, stream>>>(ws, out + OUT_PBG, f_q);
    k5_main<<<Bb*NCH, 512, 0, stream>>>(f_raw, gt_mask, alpha, ln_w, ln_b,
                                        out + OUT_PBG, ws,
                                        out + OUT_FFG, out + OUT_FBG, out + OUT_SSEM);
    k8_final<<<1, 1024, 0, stream>>>(ws, out + OUT_LOSS);
}